// Round 1
// baseline (699.206 us; speedup 1.0000x reference)
//
#include <hip/hip_runtime.h>
#include <math.h>

#define L_  12
#define B_  32
#define H_  12
#define N1_ 197
#define D_  768
#define HD_ 64
#define R_  19

// ---------------------------------------------------------------------------
// K1: head-mean + row-normalize fold.
// P[l,b,i,j] = (sum_h attn[l,b,h,i,j]) / (S_i + 12),  d[l,b,i] = 12/(S_i+12)
// where S_i = sum_j sum_h attn[l,b,h,i,j].
// One wave per (l,b,i) row; 4 waves per block. Reads 715MB -> BW-bound.
// ---------------------------------------------------------------------------
__global__ __launch_bounds__(256) void k1_mean_norm(const float* __restrict__ attn,
                                                    float* __restrict__ P,
                                                    float* __restrict__ dvec) {
  int wid = threadIdx.x >> 6;
  int t   = threadIdx.x & 63;
  int row = blockIdx.x * 4 + wid;          // 0 .. L*B*N1-1  (lb*197 + i)
  int i   = row % N1_;
  int lb  = row / N1_;
  const float* base = attn + (size_t)lb * (H_ * N1_ * N1_) + (size_t)i * N1_;
  float c0 = 0.f, c1 = 0.f, c2 = 0.f, c3 = 0.f;
#pragma unroll
  for (int h = 0; h < H_; ++h) {
    const float* p = base + (size_t)h * (N1_ * N1_);
    c0 += p[t];
    c1 += p[t + 64];
    c2 += p[t + 128];
    c3 += (t < 5) ? p[t + 192] : 0.f;
  }
  float rs = c0 + c1 + c2 + c3;
#pragma unroll
  for (int o = 32; o; o >>= 1) rs += __shfl_xor(rs, o);
  float inv = 1.f / (rs + 12.f);
  float* Pr = P + (size_t)row * N1_;
  Pr[t]       = c0 * inv;
  Pr[t + 64]  = c1 * inv;
  Pr[t + 128] = c2 * inv;
  if (t < 5) Pr[t + 192] = c3 * inv;
  if (t == 0) dvec[row] = 12.f * inv;
}

// ---------------------------------------------------------------------------
// K2: per-batch rollout chain (row 0 only) + top-k selection.
// v^T <- e0^T A[11]; then v^T <- v^T A[l] for l=10..0.
// v_new[j] = sum_i v[i]*P[l,b,i,j] + v[j]*d[l,b,j].
// 512 threads: i-range split in 2 halves (ILP), unroll-8 accumulators.
// Then top-19 argmax selection (value desc, index asc == jax.lax.top_k),
// storing GLOBAL x-row indices b*197 + (n+1) for the q-gather GEMM.
// ---------------------------------------------------------------------------
__global__ __launch_bounds__(512) void k2_chain_topk(const float* __restrict__ P,
                                                     const float* __restrict__ dvec,
                                                     int* __restrict__ gidx) {
  int b = blockIdx.x;
  __shared__ float v[N1_];
  __shared__ float part[2][N1_];
  int t    = threadIdx.x;        // 0..511
  int half = t >> 8;             // 0/1
  int j    = t & 255;            // column this thread owns (if <197)

  if (t < N1_) {
    const float* Pr = P + ((size_t)(11 * B_ + b) * N1_) * N1_;   // layer 11, row 0
    v[t] = Pr[t] + (t == 0 ? dvec[(11 * B_ + b) * N1_] : 0.f);
  }
  __syncthreads();

  for (int l = 10; l >= 0; --l) {
    if (j < N1_) {
      const float* Pc = P + ((size_t)(l * B_ + b) * N1_) * N1_ + j;
      float a[8] = {0.f, 0.f, 0.f, 0.f, 0.f, 0.f, 0.f, 0.f};
      int ibeg = half ? 96 : 0;
      int iend = half ? N1_ : 96;
      int i = ibeg;
      for (; i + 8 <= iend; i += 8) {
#pragma unroll
        for (int u = 0; u < 8; ++u)
          a[u] += v[i + u] * Pc[(size_t)(i + u) * N1_];
      }
      for (; i < iend; ++i) a[0] += v[i] * Pc[(size_t)i * N1_];
      float s = ((a[0] + a[1]) + (a[2] + a[3])) + ((a[4] + a[5]) + (a[6] + a[7]));
      if (half == 0) s += v[j] * dvec[(l * B_ + b) * N1_ + j];   // diagonal term once
      part[half][j] = s;
    }
    __syncthreads();
    if (t < N1_) v[t] = part[0][t] + part[1][t];
    __syncthreads();
  }

  // top-k over cls = v[1..196]
  if (t < 64) {
    float val[4];
    int   idx[4];
#pragma unroll
    for (int c = 0; c < 4; ++c) {
      int n = t + c * 64;
      bool ok = (n < N1_ - 1);
      val[c] = ok ? v[n + 1] : -1e30f;
      idx[c] = ok ? n : (1 << 20);
    }
    for (int r = 0; r < R_; ++r) {
      float bv = val[0];
      int   bi = idx[0];
#pragma unroll
      for (int c = 1; c < 4; ++c)
        if (val[c] > bv || (val[c] == bv && idx[c] < bi)) { bv = val[c]; bi = idx[c]; }
#pragma unroll
      for (int o = 32; o; o >>= 1) {
        float ov = __shfl_xor(bv, o);
        int   oi = __shfl_xor(bi, o);
        if (ov > bv || (ov == bv && oi < bi)) { bv = ov; bi = oi; }
      }
      if (t == 0) gidx[b * R_ + r] = b * N1_ + bi + 1;
#pragma unroll
      for (int c = 0; c < 4; ++c)
        if (idx[c] == bi) val[c] = -1e30f;
    }
  }
}

// ---------------------------------------------------------------------------
// Generic f32 GEMM:  C[m, n] = sum_k A[row(m), k] * W(n)[k]  (+ bias[n])
// "NT" layout: both A rows and W rows contiguous along K.
// row(m) = gidx ? gidx[m] : m.  W(n) = n<nsplit ? W0 row n : W1 row n-nsplit.
// 128x128 tile, BK=16, 256 threads, 8x8 microtile, LDS-staged (transposed).
// ---------------------------------------------------------------------------
__global__ __launch_bounds__(256) void gemm_nt(const float* __restrict__ A,
                                               const int* __restrict__ gidx,
                                               const float* __restrict__ W0,
                                               const float* __restrict__ W1,
                                               int nsplit,
                                               const float* __restrict__ bias,
                                               float* __restrict__ C,
                                               int M, int K, int ldc) {
  __shared__ float As[16][132];
  __shared__ float Ws[16][132];
  int tid = threadIdx.x;
  int tx = tid & 15, ty = tid >> 4;
  int bm = blockIdx.x, bn = blockIdx.y;

  const float* aptr[2];
  const float* wptr[2];
#pragma unroll
  for (int c = 0; c < 2; ++c) {
    int idx = tid + c * 256;               // 0..511
    int row = idx >> 2;                    // 0..127
    int ks  = (idx & 3) * 4;               // 0,4,8,12
    int r = bm * 128 + row;
    if (r >= M) r = M - 1;                 // clamp (stores are guarded)
    int src = gidx ? gidx[r] : r;
    aptr[c] = A + (size_t)src * K + ks;
    int n = bn * 128 + row;
    const float* Wb = (n < nsplit) ? (W0 + (size_t)n * K)
                                   : (W1 + (size_t)(n - nsplit) * K);
    wptr[c] = Wb + ks;
  }

  float acc[8][8] = {};
  for (int k0 = 0; k0 < K; k0 += 16) {
#pragma unroll
    for (int c = 0; c < 2; ++c) {
      int idx = tid + c * 256;
      int row = idx >> 2;
      int ks  = (idx & 3) * 4;
      float4 a = *(const float4*)(aptr[c] + k0);
      As[ks + 0][row] = a.x; As[ks + 1][row] = a.y;
      As[ks + 2][row] = a.z; As[ks + 3][row] = a.w;
      float4 w = *(const float4*)(wptr[c] + k0);
      Ws[ks + 0][row] = w.x; Ws[ks + 1][row] = w.y;
      Ws[ks + 2][row] = w.z; Ws[ks + 3][row] = w.w;
    }
    __syncthreads();
#pragma unroll
    for (int kk = 0; kk < 16; ++kk) {
      float a[8], bb[8];
      *(float4*)&a[0]  = *(const float4*)&As[kk][ty * 8];
      *(float4*)&a[4]  = *(const float4*)&As[kk][ty * 8 + 4];
      *(float4*)&bb[0] = *(const float4*)&Ws[kk][tx * 8];
      *(float4*)&bb[4] = *(const float4*)&Ws[kk][tx * 8 + 4];
#pragma unroll
      for (int ii = 0; ii < 8; ++ii)
#pragma unroll
        for (int jj = 0; jj < 8; ++jj)
          acc[ii][jj] += a[ii] * bb[jj];
    }
    __syncthreads();
  }

#pragma unroll
  for (int ii = 0; ii < 8; ++ii) {
    int m = bm * 128 + ty * 8 + ii;
    if (m < M) {
#pragma unroll
      for (int jj = 0; jj < 8; jj += 4) {
        int n = bn * 128 + tx * 8 + jj;
        float4 o;
        o.x = acc[ii][jj];     o.y = acc[ii][jj + 1];
        o.z = acc[ii][jj + 2]; o.w = acc[ii][jj + 3];
        if (bias) { o.x += bias[n]; o.y += bias[n + 1]; o.z += bias[n + 2]; o.w += bias[n + 3]; }
        *(float4*)&C[(size_t)m * ldc + n] = o;
      }
    }
  }
}

// ---------------------------------------------------------------------------
// K5: per-(b,h) attention. K staged in LDS ([197][68] padding -> conflict-free
// column reads), q staged, scores+softmax in LDS, PV with coalesced V reads.
// ---------------------------------------------------------------------------
__global__ __launch_bounds__(256) void k5_attn(const float* __restrict__ kvb,
                                               const float* __restrict__ qb,
                                               float* __restrict__ ctx) {
  int bh = blockIdx.x;
  int b = bh / H_, h = bh % H_;
  __shared__ float ks[N1_][68];
  __shared__ float qs[R_][64];
  __shared__ float sc[R_][200];
  __shared__ float rsum[R_];
  int t = threadIdx.x;
  int lane = t & 63, wid = t >> 6;

  const float* kbase = kvb + (size_t)b * N1_ * 1536 + h * 64;       // k half
  for (int n = wid; n < N1_; n += 4)
    ks[n][lane] = kbase[(size_t)n * 1536 + lane];
  const float* qrow = qb + (size_t)b * R_ * D_ + h * 64;
  for (int e = t; e < R_ * 64; e += 256) {
    int r = e >> 6, d = e & 63;
    qs[r][d] = qrow[(size_t)r * D_ + d];
  }
  __syncthreads();

  // phase 1: thread t = key n; S[r][n] = 0.125 * q[r].k[n]
  if (t < N1_) {
    float accr[R_];
#pragma unroll
    for (int r = 0; r < R_; ++r) accr[r] = 0.f;
#pragma unroll
    for (int d0 = 0; d0 < 4; ++d0) {
      float4 k0 = *(const float4*)&ks[t][d0 * 16 + 0];
      float4 k1 = *(const float4*)&ks[t][d0 * 16 + 4];
      float4 k2 = *(const float4*)&ks[t][d0 * 16 + 8];
      float4 k3 = *(const float4*)&ks[t][d0 * 16 + 12];
#pragma unroll
      for (int r = 0; r < R_; ++r) {
        float4 q0 = *(const float4*)&qs[r][d0 * 16 + 0];
        float4 q1 = *(const float4*)&qs[r][d0 * 16 + 4];
        float4 q2 = *(const float4*)&qs[r][d0 * 16 + 8];
        float4 q3 = *(const float4*)&qs[r][d0 * 16 + 12];
        accr[r] += k0.x * q0.x + k0.y * q0.y + k0.z * q0.z + k0.w * q0.w
                 + k1.x * q1.x + k1.y * q1.y + k1.z * q1.z + k1.w * q1.w
                 + k2.x * q2.x + k2.y * q2.y + k2.z * q2.z + k2.w * q2.w
                 + k3.x * q3.x + k3.y * q3.y + k3.z * q3.z + k3.w * q3.w;
      }
    }
#pragma unroll
    for (int r = 0; r < R_; ++r) sc[r][t] = accr[r] * 0.125f;
  }
  __syncthreads();

  // phase 2: softmax over n for rows r = wid, wid+4, ...
  for (int r = wid; r < R_; r += 4) {
    float x0 = sc[r][lane];
    float x1 = sc[r][lane + 64];
    float x2 = sc[r][lane + 128];
    bool ok3 = (lane + 192 < N1_);
    float x3 = ok3 ? sc[r][lane + 192] : -1e30f;
    float m = fmaxf(fmaxf(x0, x1), fmaxf(x2, x3));
#pragma unroll
    for (int o = 32; o; o >>= 1) m = fmaxf(m, __shfl_xor(m, o));
    float e0 = expf(x0 - m), e1 = expf(x1 - m), e2 = expf(x2 - m);
    float e3 = ok3 ? expf(x3 - m) : 0.f;
    float s = e0 + e1 + e2 + e3;
#pragma unroll
    for (int o = 32; o; o >>= 1) s += __shfl_xor(s, o);
    sc[r][lane] = e0; sc[r][lane + 64] = e1; sc[r][lane + 128] = e2;
    if (ok3) sc[r][lane + 192] = e3;
    if (lane == 0) rsum[r] = s;
  }
  __syncthreads();

  // phase 3: PV. thread (wid, lane=d). rows r = wid + 4k.
  const float* vb = kvb + (size_t)b * N1_ * 1536 + 768 + h * 64 + lane;
  int r0 = wid, r1 = wid + 4, r2 = wid + 8, r3 = wid + 12, r4 = wid + 16;
  bool has4 = (r4 < R_);
  float a0 = 0.f, a1 = 0.f, a2 = 0.f, a3 = 0.f, a4 = 0.f;
  for (int n = 0; n < N1_; ++n) {
    float vv = vb[(size_t)n * 1536];
    a0 += sc[r0][n] * vv;
    a1 += sc[r1][n] * vv;
    a2 += sc[r2][n] * vv;
    a3 += sc[r3][n] * vv;
    if (has4) a4 += sc[r4][n] * vv;
  }
  float* cb = ctx + (size_t)(b * R_) * D_ + h * 64 + lane;
  cb[(size_t)r0 * D_] = a0 / rsum[r0];
  cb[(size_t)r1 * D_] = a1 / rsum[r1];
  cb[(size_t)r2 * D_] = a2 / rsum[r2];
  cb[(size_t)r3 * D_] = a3 / rsum[r3];
  if (has4) cb[(size_t)r4 * D_] = a4 / rsum[r4];
}

// ---------------------------------------------------------------------------
extern "C" void kernel_launch(void* const* d_in, const int* in_sizes, int n_in,
                              void* d_out, int out_size, void* d_ws, size_t ws_size,
                              hipStream_t stream) {
  const float* x      = (const float*)d_in[0];
  const float* attn   = (const float*)d_in[1];
  const float* q_w    = (const float*)d_in[2];
  const float* k_w    = (const float*)d_in[3];
  const float* v_w    = (const float*)d_in[4];
  const float* proj_w = (const float*)d_in[5];
  const float* proj_b = (const float*)d_in[6];
  float* out = (float*)d_out;

  // workspace layout (floats): total ~102.4 MB
  float* ws   = (float*)d_ws;
  float* P    = ws;                                        // L*B*N1*N1 = 14,902,656
  float* dvec = P + (size_t)L_ * B_ * N1_ * N1_;           // L*B*N1    =     75,648
  int*   gidx = (int*)(dvec + (size_t)L_ * B_ * N1_);      // B*R ints (pad to 640)
  float* kvb  = (float*)(gidx + 640);                      // B*N1*1536 =  9,682,944
  float* qbuf = kvb + (size_t)B_ * N1_ * 1536;             // B*R*D     =    466,944
  float* ctx  = qbuf + (size_t)B_ * R_ * D_;               // B*R*D     =    466,944

  // 1) head-mean + normalize  (reads the 715MB attn_stack once)
  hipLaunchKernelGGL(k1_mean_norm, dim3((L_ * B_ * N1_) / 4), dim3(256), 0, stream,
                     attn, P, dvec);
  // 2) rollout chain (row 0) + top-19 indices
  hipLaunchKernelGGL(k2_chain_topk, dim3(B_), dim3(512), 0, stream, P, dvec, gidx);
  // 3) K,V projections fused: kvb[token][0:768]=x@k_w.T, [768:1536]=x@v_w.T
  hipLaunchKernelGGL(gemm_nt, dim3(50, 12), dim3(256), 0, stream,
                     x, (const int*)nullptr, k_w, v_w, 768, (const float*)nullptr,
                     kvb, B_ * N1_, D_, 1536);
  // 4) q projection of gathered top-R tokens
  hipLaunchKernelGGL(gemm_nt, dim3(5, 6), dim3(256), 0, stream,
                     x, gidx, q_w, q_w, 1 << 30, (const float*)nullptr,
                     qbuf, B_ * R_, D_, D_);
  // 5) attention per (b,h)
  hipLaunchKernelGGL(k5_attn, dim3(B_ * H_), dim3(256), 0, stream, kvb, qbuf, ctx);
  // 6) output projection + bias -> d_out
  hipLaunchKernelGGL(gemm_nt, dim3(5, 6), dim3(256), 0, stream,
                     ctx, (const int*)nullptr, proj_w, proj_w, 1 << 30, proj_b,
                     out, B_ * R_, D_, D_);
}

// Round 2
// 413.166 us; speedup vs baseline: 1.6923x; 1.6923x over previous
//
#include <hip/hip_runtime.h>
#include <math.h>

#define L_  12
#define B_  32
#define H_  12
#define N1_ 197
#define D_  768
#define HD_ 64
#define R_  19

typedef __attribute__((ext_vector_type(8))) short short8;
typedef __attribute__((ext_vector_type(4))) float f32x4;

// ---------------------------------------------------------------------------
// K1: head-mean + row-normalize fold.
// P[l,b,i,j] = (sum_h attn[l,b,h,i,j]) / (S_i + 12),  d[l,b,i] = 12/(S_i+12)
// ---------------------------------------------------------------------------
__global__ __launch_bounds__(256) void k1_mean_norm(const float* __restrict__ attn,
                                                    float* __restrict__ P,
                                                    float* __restrict__ dvec) {
  int wid = threadIdx.x >> 6;
  int t   = threadIdx.x & 63;
  int row = blockIdx.x * 4 + wid;          // 0 .. L*B*N1-1  (lb*197 + i)
  int i   = row % N1_;
  int lb  = row / N1_;
  const float* base = attn + (size_t)lb * (H_ * N1_ * N1_) + (size_t)i * N1_;
  float c0 = 0.f, c1 = 0.f, c2 = 0.f, c3 = 0.f;
#pragma unroll
  for (int h = 0; h < H_; ++h) {
    const float* p = base + (size_t)h * (N1_ * N1_);
    c0 += p[t];
    c1 += p[t + 64];
    c2 += p[t + 128];
    c3 += (t < 5) ? p[t + 192] : 0.f;
  }
  float rs = c0 + c1 + c2 + c3;
#pragma unroll
  for (int o = 32; o; o >>= 1) rs += __shfl_xor(rs, o);
  float inv = 1.f / (rs + 12.f);
  float* Pr = P + (size_t)row * N1_;
  Pr[t]       = c0 * inv;
  Pr[t + 64]  = c1 * inv;
  Pr[t + 128] = c2 * inv;
  if (t < 5) Pr[t + 192] = c3 * inv;
  if (t == 0) dvec[row] = 12.f * inv;
}

// ---------------------------------------------------------------------------
// K2: per-batch rollout chain (row 0 only) + top-k selection.
// ---------------------------------------------------------------------------
__global__ __launch_bounds__(512) void k2_chain_topk(const float* __restrict__ P,
                                                     const float* __restrict__ dvec,
                                                     int* __restrict__ gidx) {
  int b = blockIdx.x;
  __shared__ float v[N1_];
  __shared__ float part[2][N1_];
  int t    = threadIdx.x;        // 0..511
  int half = t >> 8;             // 0/1
  int j    = t & 255;            // column this thread owns (if <197)

  if (t < N1_) {
    const float* Pr = P + ((size_t)(11 * B_ + b) * N1_) * N1_;   // layer 11, row 0
    v[t] = Pr[t] + (t == 0 ? dvec[(11 * B_ + b) * N1_] : 0.f);
  }
  __syncthreads();

  for (int l = 10; l >= 0; --l) {
    if (j < N1_) {
      const float* Pc = P + ((size_t)(l * B_ + b) * N1_) * N1_ + j;
      float a[8] = {0.f, 0.f, 0.f, 0.f, 0.f, 0.f, 0.f, 0.f};
      int ibeg = half ? 96 : 0;
      int iend = half ? N1_ : 96;
      int i = ibeg;
      for (; i + 8 <= iend; i += 8) {
#pragma unroll
        for (int u = 0; u < 8; ++u)
          a[u] += v[i + u] * Pc[(size_t)(i + u) * N1_];
      }
      for (; i < iend; ++i) a[0] += v[i] * Pc[(size_t)i * N1_];
      float s = ((a[0] + a[1]) + (a[2] + a[3])) + ((a[4] + a[5]) + (a[6] + a[7]));
      if (half == 0) s += v[j] * dvec[(l * B_ + b) * N1_ + j];   // diagonal term once
      part[half][j] = s;
    }
    __syncthreads();
    if (t < N1_) v[t] = part[0][t] + part[1][t];
    __syncthreads();
  }

  // top-k over cls = v[1..196]; jax tie-break: value desc, index asc
  if (t < 64) {
    float val[4];
    int   idx[4];
#pragma unroll
    for (int c = 0; c < 4; ++c) {
      int n = t + c * 64;
      bool ok = (n < N1_ - 1);
      val[c] = ok ? v[n + 1] : -1e30f;
      idx[c] = ok ? n : (1 << 20);
    }
    for (int r = 0; r < R_; ++r) {
      float bv = val[0];
      int   bi = idx[0];
#pragma unroll
      for (int c = 1; c < 4; ++c)
        if (val[c] > bv || (val[c] == bv && idx[c] < bi)) { bv = val[c]; bi = idx[c]; }
#pragma unroll
      for (int o = 32; o; o >>= 1) {
        float ov = __shfl_xor(bv, o);
        int   oi = __shfl_xor(bi, o);
        if (ov > bv || (ov == bv && oi < bi)) { bv = ov; bi = oi; }
      }
      if (t == 0) gidx[b * R_ + r] = b * N1_ + bi + 1;
#pragma unroll
      for (int c = 0; c < 4; ++c)
        if (idx[c] == bi) val[c] = -1e30f;
    }
  }
}

// ---------------------------------------------------------------------------
// f32 -> bf16 hi/lo split converters. hi = rn(f), lo = rn(f - hi).
// Error of hi*hi + hi*lo + lo*hi vs f32 product ~ 2^-16 relative.
// ---------------------------------------------------------------------------
__device__ inline ushort f2bf_rn(float f) {
  unsigned u = __float_as_uint(f);
  unsigned r = (u + 0x7FFFu + ((u >> 16) & 1u)) >> 16;
  return (ushort)r;
}
__device__ inline float bf2f(ushort h) { return __uint_as_float((unsigned)h << 16); }

__global__ __launch_bounds__(256) void conv_split(const float* __restrict__ src,
                                                  ushort* __restrict__ hi,
                                                  ushort* __restrict__ lo, int n4) {
  int i = blockIdx.x * 256 + threadIdx.x;
  if (i >= n4) return;
  float4 f = ((const float4*)src)[i];
  ushort4 h, l;
  h.x = f2bf_rn(f.x); l.x = f2bf_rn(f.x - bf2f(h.x));
  h.y = f2bf_rn(f.y); l.y = f2bf_rn(f.y - bf2f(h.y));
  h.z = f2bf_rn(f.z); l.z = f2bf_rn(f.z - bf2f(h.z));
  h.w = f2bf_rn(f.w); l.w = f2bf_rn(f.w - bf2f(h.w));
  ((ushort4*)hi)[i] = h;
  ((ushort4*)lo)[i] = l;
}

// 4 weight matrices (768x768 each) stacked: [k_w; v_w; q_w; proj_w]
__global__ __launch_bounds__(256) void conv_w4(const float* __restrict__ w0,
                                               const float* __restrict__ w1,
                                               const float* __restrict__ w2,
                                               const float* __restrict__ w3,
                                               ushort* __restrict__ hi,
                                               ushort* __restrict__ lo) {
  int i = blockIdx.x * 256 + threadIdx.x;   // float4 index, 4*147456 total
  int mat = i / 147456;
  int off = i - mat * 147456;
  const float* src = (mat == 0) ? w0 : (mat == 1) ? w1 : (mat == 2) ? w2 : w3;
  float4 f = ((const float4*)src)[off];
  ushort4 h, l;
  h.x = f2bf_rn(f.x); l.x = f2bf_rn(f.x - bf2f(h.x));
  h.y = f2bf_rn(f.y); l.y = f2bf_rn(f.y - bf2f(h.y));
  h.z = f2bf_rn(f.z); l.z = f2bf_rn(f.z - bf2f(h.z));
  h.w = f2bf_rn(f.w); l.w = f2bf_rn(f.w - bf2f(h.w));
  ((ushort4*)hi)[i] = h;
  ((ushort4*)lo)[i] = l;
}

// ---------------------------------------------------------------------------
// Split-bf16 MFMA GEMM:  C[m,n] = sum_k A[row(m),k] * W[n,k]  (+ bias[n])
// A given as (Ah,Al) bf16 MxK row-major; W as (Wh,Wl) bf16 NxK row-major.
// row(m) = gidx ? gidx[m] : m.
// Tile BM x BN, BK=32, 256 threads = 4 waves in 2x2. Each wave: (BM/2)x(BN/2)
// via MF x NF 16x16 fragments. mfma_f32_16x16x32_bf16:
//   A frag: row = lane&15, k = 8*(lane>>4)+j  (8 contiguous bf16 -> ds_read_b128)
//   C/D:    col = lane&15, row = 4*(lane>>4)+reg   [m89-verified]
// LDS row stride 40 bf16 (80B) -> fragment reads are 2-way bank (free, m136).
// Register prefetch of next k-tile hides global latency under MFMA.
// ---------------------------------------------------------------------------
#define PK 40
template <int BM, int BN, int MF, int NF>
__global__ __launch_bounds__(256) void gemm_mfma(const ushort* __restrict__ Ah,
                                                 const ushort* __restrict__ Al,
                                                 const int* __restrict__ gidx,
                                                 const ushort* __restrict__ Wh,
                                                 const ushort* __restrict__ Wl,
                                                 const float* __restrict__ bias,
                                                 float* __restrict__ C,
                                                 int M, int K, int ldc) {
  __shared__ __attribute__((aligned(16))) ushort As[2][BM][PK];
  __shared__ __attribute__((aligned(16))) ushort Bs[2][BN][PK];
  constexpr int TPRA = 256 / BM;          // threads per A row
  constexpr int EPTA = 32 / TPRA;         // bf16 elems per thread (A)
  constexpr int NLA  = EPTA / 8;          // short8 loads per thread per half (A)
  constexpr int TPRB = 256 / BN;
  constexpr int EPTB = 32 / TPRB;
  constexpr int NLB  = EPTB / 8;

  int tid  = threadIdx.x;
  int lane = tid & 63, wid = tid >> 6;
  int wr = wid >> 1, wc = wid & 1;
  int lr = lane & 15, lk = lane >> 4;
  int bm = blockIdx.x, bn = blockIdx.y;

  int arow_s = tid / TPRA;
  int akoff  = (tid % TPRA) * EPTA;
  int ar = bm * BM + arow_s; if (ar >= M) ar = M - 1;
  int asrc = gidx ? gidx[ar] : ar;
  const ushort* ap_h = Ah + (size_t)asrc * K + akoff;
  const ushort* ap_l = Al + (size_t)asrc * K + akoff;

  int brow_s = tid / TPRB;
  int bkoff  = (tid % TPRB) * EPTB;
  int wrow = bn * BN + brow_s;
  const ushort* wp_h = Wh + (size_t)wrow * K + bkoff;
  const ushort* wp_l = Wl + (size_t)wrow * K + bkoff;

  f32x4 acc[MF][NF] = {};

  short8 pa[2][NLA], pb[2][NLB];
#pragma unroll
  for (int u = 0; u < NLA; ++u) {
    pa[0][u] = *(const short8*)(ap_h + u * 8);
    pa[1][u] = *(const short8*)(ap_l + u * 8);
  }
#pragma unroll
  for (int u = 0; u < NLB; ++u) {
    pb[0][u] = *(const short8*)(wp_h + u * 8);
    pb[1][u] = *(const short8*)(wp_l + u * 8);
  }

  for (int k0 = 0; k0 < K; k0 += 32) {
#pragma unroll
    for (int u = 0; u < NLA; ++u) {
      *(short8*)&As[0][arow_s][akoff + u * 8] = pa[0][u];
      *(short8*)&As[1][arow_s][akoff + u * 8] = pa[1][u];
    }
#pragma unroll
    for (int u = 0; u < NLB; ++u) {
      *(short8*)&Bs[0][brow_s][bkoff + u * 8] = pb[0][u];
      *(short8*)&Bs[1][brow_s][bkoff + u * 8] = pb[1][u];
    }
    __syncthreads();

    int kn = k0 + 32;
    if (kn < K) {
#pragma unroll
      for (int u = 0; u < NLA; ++u) {
        pa[0][u] = *(const short8*)(ap_h + kn + u * 8);
        pa[1][u] = *(const short8*)(ap_l + kn + u * 8);
      }
#pragma unroll
      for (int u = 0; u < NLB; ++u) {
        pb[0][u] = *(const short8*)(wp_h + kn + u * 8);
        pb[1][u] = *(const short8*)(wp_l + kn + u * 8);
      }
    }

    short8 af[2][MF], bf[2][NF];
#pragma unroll
    for (int m = 0; m < MF; ++m) {
      af[0][m] = *(const short8*)&As[0][wr * (BM / 2) + m * 16 + lr][lk * 8];
      af[1][m] = *(const short8*)&As[1][wr * (BM / 2) + m * 16 + lr][lk * 8];
    }
#pragma unroll
    for (int n = 0; n < NF; ++n) {
      bf[0][n] = *(const short8*)&Bs[0][wc * (BN / 2) + n * 16 + lr][lk * 8];
      bf[1][n] = *(const short8*)&Bs[1][wc * (BN / 2) + n * 16 + lr][lk * 8];
    }
#pragma unroll
    for (int m = 0; m < MF; ++m)
#pragma unroll
      for (int n = 0; n < NF; ++n) {
        acc[m][n] = __builtin_amdgcn_mfma_f32_16x16x32_bf16(af[0][m], bf[0][n], acc[m][n], 0, 0, 0);
        acc[m][n] = __builtin_amdgcn_mfma_f32_16x16x32_bf16(af[0][m], bf[1][n], acc[m][n], 0, 0, 0);
        acc[m][n] = __builtin_amdgcn_mfma_f32_16x16x32_bf16(af[1][m], bf[0][n], acc[m][n], 0, 0, 0);
      }
    __syncthreads();
  }

#pragma unroll
  for (int m = 0; m < MF; ++m) {
    int row0 = bm * BM + wr * (BM / 2) + m * 16 + lk * 4;
#pragma unroll
    for (int i = 0; i < 4; ++i) {
      int row = row0 + i;
      if (row < M) {
#pragma unroll
        for (int n = 0; n < NF; ++n) {
          int col = bn * BN + wc * (BN / 2) + n * 16 + lr;
          float vv = acc[m][n][i];
          if (bias) vv += bias[col];
          C[(size_t)row * ldc + col] = vv;
        }
      }
    }
  }
}

// ---------------------------------------------------------------------------
// K5: per-(b,h) attention (f32, small).
// ---------------------------------------------------------------------------
__global__ __launch_bounds__(256) void k5_attn(const float* __restrict__ kvb,
                                               const float* __restrict__ qb,
                                               float* __restrict__ ctx) {
  int bh = blockIdx.x;
  int b = bh / H_, h = bh % H_;
  __shared__ float ks[N1_][68];
  __shared__ float qs[R_][64];
  __shared__ float sc[R_][200];
  __shared__ float rsum[R_];
  int t = threadIdx.x;
  int lane = t & 63, wid = t >> 6;

  const float* kbase = kvb + (size_t)b * N1_ * 1536 + h * 64;       // k half
  for (int n = wid; n < N1_; n += 4)
    ks[n][lane] = kbase[(size_t)n * 1536 + lane];
  const float* qrow = qb + (size_t)b * R_ * D_ + h * 64;
  for (int e = t; e < R_ * 64; e += 256) {
    int r = e >> 6, d = e & 63;
    qs[r][d] = qrow[(size_t)r * D_ + d];
  }
  __syncthreads();

  if (t < N1_) {
    float accr[R_];
#pragma unroll
    for (int r = 0; r < R_; ++r) accr[r] = 0.f;
#pragma unroll
    for (int d0 = 0; d0 < 4; ++d0) {
      float4 k0 = *(const float4*)&ks[t][d0 * 16 + 0];
      float4 k1 = *(const float4*)&ks[t][d0 * 16 + 4];
      float4 k2 = *(const float4*)&ks[t][d0 * 16 + 8];
      float4 k3 = *(const float4*)&ks[t][d0 * 16 + 12];
#pragma unroll
      for (int r = 0; r < R_; ++r) {
        float4 q0 = *(const float4*)&qs[r][d0 * 16 + 0];
        float4 q1 = *(const float4*)&qs[r][d0 * 16 + 4];
        float4 q2 = *(const float4*)&qs[r][d0 * 16 + 8];
        float4 q3 = *(const float4*)&qs[r][d0 * 16 + 12];
        accr[r] += k0.x * q0.x + k0.y * q0.y + k0.z * q0.z + k0.w * q0.w
                 + k1.x * q1.x + k1.y * q1.y + k1.z * q1.z + k1.w * q1.w
                 + k2.x * q2.x + k2.y * q2.y + k2.z * q2.z + k2.w * q2.w
                 + k3.x * q3.x + k3.y * q3.y + k3.z * q3.z + k3.w * q3.w;
      }
    }
#pragma unroll
    for (int r = 0; r < R_; ++r) sc[r][t] = accr[r] * 0.125f;
  }
  __syncthreads();

  for (int r = wid; r < R_; r += 4) {
    float x0 = sc[r][lane];
    float x1 = sc[r][lane + 64];
    float x2 = sc[r][lane + 128];
    bool ok3 = (lane + 192 < N1_);
    float x3 = ok3 ? sc[r][lane + 192] : -1e30f;
    float m = fmaxf(fmaxf(x0, x1), fmaxf(x2, x3));
#pragma unroll
    for (int o = 32; o; o >>= 1) m = fmaxf(m, __shfl_xor(m, o));
    float e0 = expf(x0 - m), e1 = expf(x1 - m), e2 = expf(x2 - m);
    float e3 = ok3 ? expf(x3 - m) : 0.f;
    float s = e0 + e1 + e2 + e3;
#pragma unroll
    for (int o = 32; o; o >>= 1) s += __shfl_xor(s, o);
    sc[r][lane] = e0; sc[r][lane + 64] = e1; sc[r][lane + 128] = e2;
    if (ok3) sc[r][lane + 192] = e3;
    if (lane == 0) rsum[r] = s;
  }
  __syncthreads();

  const float* vb = kvb + (size_t)b * N1_ * 1536 + 768 + h * 64 + lane;
  int r0 = wid, r1 = wid + 4, r2 = wid + 8, r3 = wid + 12, r4 = wid + 16;
  bool has4 = (r4 < R_);
  float a0 = 0.f, a1 = 0.f, a2 = 0.f, a3 = 0.f, a4 = 0.f;
  for (int n = 0; n < N1_; ++n) {
    float vv = vb[(size_t)n * 1536];
    a0 += sc[r0][n] * vv;
    a1 += sc[r1][n] * vv;
    a2 += sc[r2][n] * vv;
    a3 += sc[r3][n] * vv;
    if (has4) a4 += sc[r4][n] * vv;
  }
  float* cb = ctx + (size_t)(b * R_) * D_ + h * 64 + lane;
  cb[(size_t)r0 * D_] = a0 / rsum[r0];
  cb[(size_t)r1 * D_] = a1 / rsum[r1];
  cb[(size_t)r2 * D_] = a2 / rsum[r2];
  cb[(size_t)r3 * D_] = a3 / rsum[r3];
  if (has4) cb[(size_t)r4 * D_] = a4 / rsum[r4];
}

// ---------------------------------------------------------------------------
extern "C" void kernel_launch(void* const* d_in, const int* in_sizes, int n_in,
                              void* d_out, int out_size, void* d_ws, size_t ws_size,
                              hipStream_t stream) {
  const float* x      = (const float*)d_in[0];
  const float* attn   = (const float*)d_in[1];
  const float* q_w    = (const float*)d_in[2];
  const float* k_w    = (const float*)d_in[3];
  const float* v_w    = (const float*)d_in[4];
  const float* proj_w = (const float*)d_in[5];
  const float* proj_b = (const float*)d_in[6];
  float* out = (float*)d_out;

  // workspace layout (256B aligned segments), ~133 MB total
  char* w = (char*)d_ws;
  auto take = [&](size_t bytes) { char* p = w; w += (bytes + 255) & ~(size_t)255; return p; };
  float*  P     = (float*)take((size_t)L_ * B_ * N1_ * N1_ * 4);   // 59.6 MB
  float*  dvec  = (float*)take((size_t)L_ * B_ * N1_ * 4);
  int*    gidx  = (int*)take(B_ * R_ * 4);
  float*  kvb   = (float*)take((size_t)B_ * N1_ * 1536 * 4);       // 38.7 MB
  float*  qbuf  = (float*)take((size_t)B_ * R_ * D_ * 4);
  float*  ctx   = (float*)take((size_t)B_ * R_ * D_ * 4);
  ushort* xh    = (ushort*)take((size_t)B_ * N1_ * D_ * 2);        // 9.7 MB
  ushort* xl    = (ushort*)take((size_t)B_ * N1_ * D_ * 2);
  ushort* wh    = (ushort*)take((size_t)4 * D_ * D_ * 2);          // [k;v;q;proj]
  ushort* wl    = (ushort*)take((size_t)4 * D_ * D_ * 2);
  ushort* ctxh  = (ushort*)take((size_t)B_ * R_ * D_ * 2);
  ushort* ctxl  = (ushort*)take((size_t)B_ * R_ * D_ * 2);

  const int WMAT = D_ * D_;   // 589824 elems per weight matrix

  // 1) head-mean + normalize (reads the 715MB attn_stack once; HBM floor)
  hipLaunchKernelGGL(k1_mean_norm, dim3((L_ * B_ * N1_) / 4), dim3(256), 0, stream,
                     attn, P, dvec);
  // 2) rollout chain (row 0) + top-19 indices (P still L2-warm)
  hipLaunchKernelGGL(k2_chain_topk, dim3(B_), dim3(512), 0, stream, P, dvec, gidx);
  // 3) split conversions
  hipLaunchKernelGGL(conv_split, dim3((B_ * N1_ * D_ / 4 + 255) / 256), dim3(256), 0,
                     stream, x, xh, xl, B_ * N1_ * D_ / 4);
  hipLaunchKernelGGL(conv_w4, dim3(4 * WMAT / 4 / 256), dim3(256), 0, stream,
                     k_w, v_w, q_w, proj_w, wh, wl);
  // 4) K,V projections fused: kvb[token][0:768]=x@k_w.T, [768:1536]=x@v_w.T
  hipLaunchKernelGGL((gemm_mfma<128, 128, 4, 4>), dim3(50, 12), dim3(256), 0, stream,
                     xh, xl, (const int*)nullptr, wh, wl, (const float*)nullptr,
                     kvb, B_ * N1_, D_, 1536);
  // 5) q projection of gathered top-R tokens (64x64 tiles -> 120 blocks)
  hipLaunchKernelGGL((gemm_mfma<64, 64, 2, 2>), dim3(10, 12), dim3(256), 0, stream,
                     xh, xl, gidx, wh + (size_t)2 * WMAT, wl + (size_t)2 * WMAT,
                     (const float*)nullptr, qbuf, B_ * R_, D_, D_);
  // 6) attention per (b,h)
  hipLaunchKernelGGL(k5_attn, dim3(B_ * H_), dim3(256), 0, stream, kvb, qbuf, ctx);
  // 7) ctx split + output projection + bias -> d_out
  hipLaunchKernelGGL(conv_split, dim3((B_ * R_ * D_ / 4 + 255) / 256), dim3(256), 0,
                     stream, ctx, ctxh, ctxl, B_ * R_ * D_ / 4);
  hipLaunchKernelGGL((gemm_mfma<64, 64, 2, 2>), dim3(10, 12), dim3(256), 0, stream,
                     ctxh, ctxl, (const int*)nullptr, wh + (size_t)3 * WMAT,
                     wl + (size_t)3 * WMAT, proj_b, out, B_ * R_, D_, D_);
}